// Round 2
// baseline (516.690 us; speedup 1.0000x reference)
//
#include <hip/hip_runtime.h>
#include <stdint.h>

typedef unsigned short u16;
typedef __attribute__((ext_vector_type(8))) short short8;
typedef __attribute__((ext_vector_type(4))) float f32x4;

#define MFMA16(a,b,c) __builtin_amdgcn_mfma_f32_16x16x32_bf16((a),(b),(c),0,0,0)

typedef const __attribute__((address_space(1))) void glb_void;
typedef __attribute__((address_space(3))) void lds_void;

__device__ __forceinline__ float b2f(u16 v){ return __uint_as_float(((unsigned)v)<<16); }
__device__ __forceinline__ u16 f2b(float f){
  unsigned u = __float_as_uint(f);
  u += 0x7fffu + ((u>>16)&1u);
  return (u16)(u>>16);
}

__device__ __forceinline__ void gld16(const void* g, void* l){
  __builtin_amdgcn_global_load_lds((glb_void*)g, (lds_void*)l, 16, 0, 0);
}

// stage a [128 x 64] bf16 tile (row stride gstride elems, k-contiguous) into LDS [128][64]
__device__ __forceinline__ void stage128x64(const u16* g, u16* lds, int gstride, int w, int lane){
  #pragma unroll
  for (int i=0;i<4;++i){
    int r0 = (w*4+i)*8;
    const u16* gp = g + (size_t)(r0 + (lane>>3))*gstride + (lane&7)*8;
    gld16(gp, lds + r0*64);
  }
}
// stage a [64 x 128] bf16 tile into LDS [64][128]
__device__ __forceinline__ void stage64x128(const u16* g, u16* lds, int gstride, int w, int lane){
  #pragma unroll
  for (int i=0;i<4;++i){
    int r0 = (w*4+i)*4;
    const u16* gp = g + (size_t)(r0 + (lane>>4))*gstride + (lane&15)*8;
    gld16(gp, lds + r0*128);
  }
}

// ---------------- f32 -> bf16 elementwise (weights) --------------------------------------
__global__ __launch_bounds__(256) void cvt_bf16(const float* __restrict__ x, u16* __restrict__ y, int n){
  int i = (blockIdx.x*256 + threadIdx.x)*8;
  if (i >= n) return;
  float4 a = *(const float4*)(x+i);
  float4 b = *(const float4*)(x+i+4);
  short8 o;
  o[0]=(short)f2b(a.x); o[1]=(short)f2b(a.y); o[2]=(short)f2b(a.z); o[3]=(short)f2b(a.w);
  o[4]=(short)f2b(b.x); o[5]=(short)f2b(b.y); o[6]=(short)f2b(b.z); o[7]=(short)f2b(b.w);
  *(short8*)(y+i) = o;
}

// ---------------- transpose+convert: x_f32[b][Cdim][Sdim] -> xt_bf16[b][Sdim][Cdim] -------
__global__ __launch_bounds__(256) void transp_cvt(const float* __restrict__ x, u16* __restrict__ xt,
                                                  int Cdim, int Sdim){
  __shared__ __align__(16) float t[64][68];
  const int b = blockIdx.z, c0 = blockIdx.y*64, s0 = blockIdx.x*64;
  const int tid = threadIdx.x;
  #pragma unroll
  for (int p=0;p<4;++p){
    int e = tid + p*256;
    int row = e>>4, c4 = (e&15)*4;
    *(float4*)&t[row][c4] = *(const float4*)&x[((size_t)b*Cdim + c0 + row)*Sdim + s0 + c4];
  }
  __syncthreads();
  #pragma unroll
  for (int p=0;p<2;++p){
    int e = tid + p*256;
    int row = e>>3, col8 = (e&7)*8;   // row = s index, col8.. = c indices
    short8 o;
    #pragma unroll
    for (int u=0;u<8;++u) o[u] = (short)f2b(t[col8+u][row]);
    *(short8*)&xt[((size_t)b*Sdim + s0 + row)*Cdim + c0 + col8] = o;
  }
}

// ---------------- GEMM: C[M][N] = A[M][K] * Bt[N][K]^T + bias, bf16 in, f32 acc ----------
template<bool F32OUT>
__global__ __launch_bounds__(256,2) void gemm_bt(
    const u16* __restrict__ A, const u16* __restrict__ Bt, const float* __restrict__ bias,
    void* __restrict__ Cv, int M, int N, int K,
    long sA, long sB, long sC, int bias_on_m)
{
  A  += (size_t)blockIdx.z * sA;
  Bt += (size_t)blockIdx.z * sB;
  const int m0 = blockIdx.y*128, n0 = blockIdx.x*128;
  __shared__ __align__(16) u16 As[128*64];
  __shared__ __align__(16) u16 Bs[128*64];
  const int tid = threadIdx.x, w = tid>>6, lane = tid&63;
  const int ln = lane&15, quad = lane>>4, q8 = quad*8;
  const int m0w = (w>>1)*64, n0w = (w&1)*64;
  f32x4 acc[4][4];
  #pragma unroll
  for(int i=0;i<4;++i)
    #pragma unroll
    for(int j=0;j<4;++j) acc[i][j] = f32x4{0.f,0.f,0.f,0.f};

  for (int kc=0; kc<K; kc+=64){
    __syncthreads();
    stage128x64(A  + (size_t)m0*K + kc, As, K, w, lane);
    stage128x64(Bt + (size_t)n0*K + kc, Bs, K, w, lane);
    __syncthreads();
    #pragma unroll
    for (int kk=0; kk<64; kk+=32){
      short8 af[4], bf[4];
      #pragma unroll
      for (int mt=0;mt<4;++mt) af[mt] = *(const short8*)&As[(m0w+mt*16+ln)*64 + kk + q8];
      #pragma unroll
      for (int nt=0;nt<4;++nt) bf[nt] = *(const short8*)&Bs[(n0w+nt*16+ln)*64 + kk + q8];
      #pragma unroll
      for (int mt=0;mt<4;++mt)
        #pragma unroll
        for (int nt=0;nt<4;++nt)
          acc[mt][nt] = MFMA16(af[mt], bf[nt], acc[mt][nt]);
    }
  }
  #pragma unroll
  for (int mt=0;mt<4;++mt){
    #pragma unroll
    for (int nt=0;nt<4;++nt){
      const int col = n0 + n0w + nt*16 + ln;
      const float bn = bias_on_m ? 0.f : bias[col];
      #pragma unroll
      for (int r=0;r<4;++r){
        const int row = m0 + m0w + mt*16 + quad*4 + r;
        const float bb = bias_on_m ? bias[row] : bn;
        const float val = acc[mt][nt][r] + bb;
        const size_t idx = (size_t)blockIdx.z*sC + (size_t)row*N + col;
        if (F32OUT) ((float*)Cv)[idx] = val;
        else        ((u16*)Cv)[idx]   = f2b(val);
      }
    }
  }
}

// ---------------- fused flash attention per (b, h, 128-q tile) ----------------------------
// Qb/Kb: bf16 [b][s][h*64+d]  Vb: bf16 [b][h*64+c][s]  masks f32, Ot: bf16 [b][s][h*64+c]
__global__ __launch_bounds__(256,1) void attn(
    const u16* __restrict__ Qb, const u16* __restrict__ Kb, const u16* __restrict__ Vb,
    const float* __restrict__ qk_mask, const float* __restrict__ k_mask,
    u16* __restrict__ Ot)
{
  __shared__ __align__(16) u16 Qs[128*64];
  __shared__ __align__(16) u16 Ks[128*64];
  __shared__ __align__(16) u16 Vs[64*128];
  __shared__ __align__(16) u16 Ps[4][16*128];   // per-wave, per-mt-half (16 q rows)
  const int qt = blockIdx.x, h = blockIdx.y, b = blockIdx.z;
  const int tid = threadIdx.x, w = tid>>6, lane = tid&63;
  const int ln = lane&15, quad = lane>>4, q8 = quad*8;
  const int S = 2048;
  const int q0 = qt*128;

  stage128x64(Qb + ((size_t)b*S + q0)*1024 + h*64, Qs, 1024, w, lane);

  float m_run[2][4], l_run[2][4];
  f32x4 acc_o[2][4];
  #pragma unroll
  for(int mt=0;mt<2;++mt){
    #pragma unroll
    for(int r=0;r<4;++r){ m_run[mt][r] = -1e30f; l_run[mt][r] = 0.f; }
    #pragma unroll
    for(int ct=0;ct<4;++ct) acc_o[mt][ct] = f32x4{0.f,0.f,0.f,0.f};
  }

  for (int kt=0; kt<16; ++kt){
    const int k0 = kt*128;
    __syncthreads();
    stage128x64(Kb + ((size_t)b*S + k0)*1024 + h*64, Ks, 1024, w, lane);
    stage64x128(Vb + ((size_t)b*1024 + h*64)*S + k0, Vs, S, w, lane);
    __syncthreads();

    // S-tile: q rows (wave owns 32), k cols (128)
    f32x4 sa[2][8];
    #pragma unroll
    for(int mt=0;mt<2;++mt)
      #pragma unroll
      for(int nt=0;nt<8;++nt) sa[mt][nt] = f32x4{0.f,0.f,0.f,0.f};
    #pragma unroll
    for (int kk=0; kk<64; kk+=32){
      short8 af[2], bf[8];
      #pragma unroll
      for (int mt=0;mt<2;++mt) af[mt] = *(const short8*)&Qs[(w*32+mt*16+ln)*64 + kk + q8];
      #pragma unroll
      for (int nt=0;nt<8;++nt) bf[nt] = *(const short8*)&Ks[(nt*16+ln)*64 + kk + q8];
      #pragma unroll
      for (int mt=0;mt<2;++mt)
        #pragma unroll
        for (int nt=0;nt<8;++nt)
          sa[mt][nt] = MFMA16(af[mt], bf[nt], sa[mt][nt]);
    }
    // scale + masks (qk_mask[b][k][q] f32, k_mask[b][k] f32)
    float kmv[8];
    #pragma unroll
    for (int nt=0;nt<8;++nt) kmv[nt] = k_mask[(size_t)b*S + k0 + nt*16 + ln];
    #pragma unroll
    for (int mt=0;mt<2;++mt){
      #pragma unroll
      for (int nt=0;nt<8;++nt){
        const size_t mbase = ((size_t)b*S + (size_t)(k0+nt*16+ln))*S + q0 + w*32 + mt*16 + quad*4;
        const float4 mq = *(const float4*)&qk_mask[mbase];
        sa[mt][nt][0] = sa[mt][nt][0]*0.125f + mq.x + kmv[nt];
        sa[mt][nt][1] = sa[mt][nt][1]*0.125f + mq.y + kmv[nt];
        sa[mt][nt][2] = sa[mt][nt][2]*0.125f + mq.z + kmv[nt];
        sa[mt][nt][3] = sa[mt][nt][3]*0.125f + mq.w + kmv[nt];
      }
    }
    // per mt-half: online softmax + P write + PV MFMA (Ps per-wave, in-wave DS order)
    #pragma unroll
    for (int mt=0;mt<2;++mt){
      #pragma unroll
      for (int r=0;r<4;++r){
        float mx = sa[mt][0][r];
        #pragma unroll
        for (int nt=1;nt<8;++nt) mx = fmaxf(mx, sa[mt][nt][r]);
        #pragma unroll
        for (int d=1; d<16; d<<=1) mx = fmaxf(mx, __shfl_xor(mx, d, 64));
        const float nm = fmaxf(m_run[mt][r], mx);
        const float alpha = __expf(m_run[mt][r] - nm);
        m_run[mt][r] = nm;
        float rs = 0.f;
        #pragma unroll
        for (int nt=0;nt<8;++nt){
          const float p = __expf(sa[mt][nt][r] - nm);
          rs += p;
          Ps[w][(quad*4+r)*128 + nt*16 + ln] = f2b(p);
        }
        #pragma unroll
        for (int d=1; d<16; d<<=1) rs += __shfl_xor(rs, d, 64);
        l_run[mt][r] = l_run[mt][r]*alpha + rs;
        #pragma unroll
        for (int ct=0;ct<4;++ct) acc_o[mt][ct][r] *= alpha;
      }
      #pragma unroll
      for (int kk=0; kk<128; kk+=32){
        short8 pf, vf[4];
        pf = *(const short8*)&Ps[w][ln*128 + kk + q8];
        #pragma unroll
        for (int ct=0;ct<4;++ct) vf[ct] = *(const short8*)&Vs[(ct*16+ln)*128 + kk + q8];
        #pragma unroll
        for (int ct=0;ct<4;++ct)
          acc_o[mt][ct] = MFMA16(pf, vf[ct], acc_o[mt][ct]);
      }
    }
  }
  // epilogue: Ot[b][q][h*64+c] = acc_o / l
  #pragma unroll
  for (int mt=0;mt<2;++mt){
    #pragma unroll
    for (int ct=0;ct<4;++ct){
      #pragma unroll
      for (int r=0;r<4;++r){
        const float o = acc_o[mt][ct][r] / l_run[mt][r];
        Ot[((size_t)b*S + q0 + w*32 + mt*16 + quad*4 + r)*1024 + h*64 + ct*16 + ln] = f2b(o);
      }
    }
  }
}

extern "C" void kernel_launch(void* const* d_in, const int* in_sizes, int n_in,
                              void* d_out, int out_size, void* d_ws, size_t ws_size,
                              hipStream_t stream)
{
  const float* q   = (const float*)d_in[0];
  const float* k   = (const float*)d_in[1];
  const float* v   = (const float*)d_in[2];
  const float* qkm = (const float*)d_in[3];
  const float* km  = (const float*)d_in[4];
  const float* Wq  = (const float*)d_in[5];
  const float* bq  = (const float*)d_in[6];
  const float* Wk  = (const float*)d_in[7];
  const float* bk  = (const float*)d_in[8];
  const float* Wv  = (const float*)d_in[9];
  const float* bv  = (const float*)d_in[10];
  const float* Wo  = (const float*)d_in[11];
  const float* bo  = (const float*)d_in[12];
  float* out = (float*)d_out;

  const int B=2, S=2048, E=1024;
  const long sSE = (long)S*E;
  const size_t nAct = (size_t)B*S*E;   // 4M elems
  const size_t nW   = (size_t)E*E;     // 1M elems

  u16* wT   = (u16*)d_ws;              // transposed activations / attn output (reused)
  u16* Qb   = wT  + nAct;
  u16* Kb   = Qb  + nAct;
  u16* Vb   = Kb  + nAct;
  u16* Wq16 = Vb  + nAct;
  u16* Wk16 = Wq16 + nW;
  u16* Wv16 = Wk16 + nW;
  u16* Wo16 = Wv16 + nW;

  dim3 blk(256);
  dim3 gC(nW/(256*8));
  dim3 gT(S/64, E/64, B);
  dim3 gP1(E/128, S/128, B);  // C [S][E]  (Q,K projections)
  dim3 gP2(S/128, E/128, B);  // C [E][S]  (V projection, final out)
  dim3 gA(S/128, 16, B);

  cvt_bf16<<<gC, blk, 0, stream>>>(Wq, Wq16, (int)nW);
  cvt_bf16<<<gC, blk, 0, stream>>>(Wk, Wk16, (int)nW);
  cvt_bf16<<<gC, blk, 0, stream>>>(Wv, Wv16, (int)nW);
  cvt_bf16<<<gC, blk, 0, stream>>>(Wo, Wo16, (int)nW);

  transp_cvt<<<gT, blk, 0, stream>>>(q, wT, E, S);
  gemm_bt<false><<<gP1, blk, 0, stream>>>(wT, Wq16, bq, Qb, S, E, E, sSE, 0, sSE, 0);
  transp_cvt<<<gT, blk, 0, stream>>>(k, wT, E, S);
  gemm_bt<false><<<gP1, blk, 0, stream>>>(wT, Wk16, bk, Kb, S, E, E, sSE, 0, sSE, 0);
  transp_cvt<<<gT, blk, 0, stream>>>(v, wT, E, S);
  gemm_bt<false><<<gP2, blk, 0, stream>>>(Wv16, wT, bv, Vb, E, S, E, 0, sSE, sSE, 1);
  attn<<<gA, blk, 0, stream>>>(Qb, Kb, Vb, qkm, km, wT);
  gemm_bt<true><<<gP2, blk, 0, stream>>>(Wo16, wT, bo, out, E, S, E, 0, sSE, sSE, 1);
}

// Round 3
// 345.924 us; speedup vs baseline: 1.4937x; 1.4937x over previous
//
#include <hip/hip_runtime.h>
#include <stdint.h>

typedef unsigned short u16;
typedef __attribute__((ext_vector_type(8))) short short8;
typedef __attribute__((ext_vector_type(4))) float f32x4;

#define MFMA16(a,b,c) __builtin_amdgcn_mfma_f32_16x16x32_bf16((a),(b),(c),0,0,0)

typedef const __attribute__((address_space(1))) void glb_void;
typedef __attribute__((address_space(3))) void lds_void;

__device__ __forceinline__ float b2f(u16 v){ return __uint_as_float(((unsigned)v)<<16); }
__device__ __forceinline__ u16 f2b(float f){
  unsigned u = __float_as_uint(f);
  u += 0x7fffu + ((u>>16)&1u);
  return (u16)(u>>16);
}
__device__ __forceinline__ void gld16(const void* g, void* l){
  __builtin_amdgcn_global_load_lds((glb_void*)g, (lds_void*)l, 16, 0, 0);
}

// ---- swizzled staging: LDS[row][c] = G[row][ (c/8 ^ (row&7))*8 + c%8 ]  (128 rows x 64) ----
__device__ __forceinline__ void stage128x64_sw(const u16* g, u16* lds, int gstride, int w, int lane){
  const int sub = lane>>3, c16 = lane&7;
  const int gcol = (c16 ^ sub)<<3;
  #pragma unroll
  for (int i=0;i<4;++i){
    int r0 = (w*4+i)*8;
    gld16(g + (size_t)(r0 + sub)*gstride + gcol, lds + r0*64);
  }
}
__device__ __forceinline__ const short8* frag64(const u16* lds, int row, int c16){
  return (const short8*)(lds + row*64 + ((c16 ^ (row&7))<<3));
}
// ---- 64 rows x 128, swizzle on row&15 ----
__device__ __forceinline__ void stage64x128_sw(const u16* g, u16* lds, int gstride, int w, int lane){
  const int sub = lane>>4, c16 = lane&15;
  #pragma unroll
  for (int i=0;i<4;++i){
    int r0 = (w*4+i)*4;
    int row = r0 + sub;
    gld16(g + (size_t)row*gstride + ((c16 ^ (row&15))<<3), lds + r0*128);
  }
}
__device__ __forceinline__ const short8* frag128(const u16* lds, int row, int c16){
  return (const short8*)(lds + row*128 + ((c16 ^ (row&15))<<3));
}

// ---------------- weights f32 -> bf16 (Wq pre-scaled by 0.125) ----------------------------
__global__ __launch_bounds__(256) void cvt_w(const float* __restrict__ Wq, const float* __restrict__ Wk,
                                             const float* __restrict__ Wv, const float* __restrict__ Wo,
                                             u16* __restrict__ o16, int nW){
  const int sel = blockIdx.y;
  const float* src = sel==0?Wq : sel==1?Wk : sel==2?Wv : Wo;
  const float sc = (sel==0) ? 0.125f : 1.0f;
  u16* dst = o16 + (size_t)sel*nW;
  int i = (blockIdx.x*256 + threadIdx.x)*8;
  if (i >= nW) return;
  float4 a = *(const float4*)(src+i);
  float4 b = *(const float4*)(src+i+4);
  short8 o;
  o[0]=(short)f2b(a.x*sc); o[1]=(short)f2b(a.y*sc); o[2]=(short)f2b(a.z*sc); o[3]=(short)f2b(a.w*sc);
  o[4]=(short)f2b(b.x*sc); o[5]=(short)f2b(b.y*sc); o[6]=(short)f2b(b.z*sc); o[7]=(short)f2b(b.w*sc);
  *(short8*)(dst+i) = o;
}

// ---------------- mask tile classification (64x64): 0=all zero, 1=mixed, 2=all masked -----
__global__ __launch_bounds__(256) void maskclass(const float* __restrict__ qkm, const float* __restrict__ km,
                                                 char* __restrict__ classes){
  __shared__ int az_s, an_s;
  const int b = blockIdx.z, ki = blockIdx.x, qi = blockIdx.y;
  const int k0 = ki*64, q0 = qi*64;
  const int tid = threadIdx.x;
  if (tid==0){ az_s = 1; an_s = 1; }
  __syncthreads();
  int az = 1, an = 1;
  #pragma unroll
  for (int p=0;p<4;++p){
    int e = tid + p*256;
    int row = e>>4, c4 = (e&15)*4;
    float kmv = km[(size_t)b*2048 + k0 + row];
    float4 v = *(const float4*)&qkm[((size_t)b*2048 + k0 + row)*2048 + q0 + c4];
    v.x += kmv; v.y += kmv; v.z += kmv; v.w += kmv;
    az &= (v.x==0.f) & (v.y==0.f) & (v.z==0.f) & (v.w==0.f);
    an &= (v.x<-1e3f) & (v.y<-1e3f) & (v.z<-1e3f) & (v.w<-1e3f);
  }
  if (!az) atomicAnd(&az_s, 0);
  if (!an) atomicAnd(&an_s, 0);
  __syncthreads();
  if (tid==0){
    char c = an_s ? 2 : (az_s ? 0 : 1);
    classes[((size_t)b*32 + qi)*32 + ki] = c;
  }
}

// ---------------- transpose+convert: x_f32[b][Cdim][Sdim] -> xt_bf16[b][Sdim][Cdim] -------
__global__ __launch_bounds__(256) void transp_cvt2(const float* __restrict__ x0, const float* __restrict__ x1,
                                                   u16* __restrict__ y0, u16* __restrict__ y1,
                                                   int Cdim, int Sdim, int nb){
  __shared__ __align__(16) float t[64][72];
  const int z = blockIdx.z, b = z % nb, sel = z / nb;
  const float* x = sel ? x1 : x0;
  u16* xt = sel ? y1 : y0;
  const int c0 = blockIdx.y*64, s0 = blockIdx.x*64;
  const int tid = threadIdx.x;
  #pragma unroll
  for (int p=0;p<4;++p){
    int e = tid + p*256;
    int row = e>>4, c4 = (e&15)*4;
    *(float4*)&t[row][c4] = *(const float4*)&x[((size_t)b*Cdim + c0 + row)*Sdim + s0 + c4];
  }
  __syncthreads();
  #pragma unroll
  for (int p=0;p<2;++p){
    int e = tid + p*256;
    int row = e>>3, col8 = (e&7)*8;
    short8 o;
    #pragma unroll
    for (int u=0;u<8;++u) o[u] = (short)f2b(t[col8+u][row]);
    *(short8*)&xt[((size_t)b*Sdim + s0 + row)*Cdim + c0 + col8] = o;
  }
}

// ---------------- GEMM core: C[M][N] = A[M][K]*Bt[N][K]^T + bias*bscale -------------------
template<bool F32OUT>
__device__ __forceinline__ void gemm_core(
    const u16* __restrict__ A, const u16* __restrict__ Bt, const float* __restrict__ bias,
    float bscale, void* __restrict__ Cv, size_t cbase, int N, int K, int bias_on_m,
    int m0, int n0, u16* As, u16* Bs)
{
  const int tid = threadIdx.x, w = tid>>6, lane = tid&63;
  const int ln = lane&15, quad = lane>>4;
  const int m0w = (w>>1)*64, n0w = (w&1)*64;
  f32x4 acc[4][4];
  #pragma unroll
  for(int i=0;i<4;++i)
    #pragma unroll
    for(int j=0;j<4;++j) acc[i][j] = f32x4{0.f,0.f,0.f,0.f};

  for (int kc=0; kc<K; kc+=64){
    __syncthreads();
    stage128x64_sw(A  + (size_t)m0*K + kc, As, K, w, lane);
    stage128x64_sw(Bt + (size_t)n0*K + kc, Bs, K, w, lane);
    __syncthreads();
    #pragma unroll
    for (int kk=0; kk<64; kk+=32){
      const int c16 = (kk>>3) + quad;
      short8 af[4], bf[4];
      #pragma unroll
      for (int mt=0;mt<4;++mt) af[mt] = *frag64(As, m0w+mt*16+ln, c16);
      #pragma unroll
      for (int nt=0;nt<4;++nt) bf[nt] = *frag64(Bs, n0w+nt*16+ln, c16);
      #pragma unroll
      for (int mt=0;mt<4;++mt)
        #pragma unroll
        for (int nt=0;nt<4;++nt)
          acc[mt][nt] = MFMA16(af[mt], bf[nt], acc[mt][nt]);
    }
  }
  #pragma unroll
  for (int mt=0;mt<4;++mt){
    #pragma unroll
    for (int nt=0;nt<4;++nt){
      const int col = n0 + n0w + nt*16 + ln;
      const float bn = bias_on_m ? 0.f : bias[col]*bscale;
      #pragma unroll
      for (int r=0;r<4;++r){
        const int row = m0 + m0w + mt*16 + quad*4 + r;
        const float bb = bias_on_m ? bias[row]*bscale : bn;
        const float val = acc[mt][nt][r] + bb;
        const size_t idx = cbase + (size_t)row*N + col;
        if (F32OUT) ((float*)Cv)[idx] = val;
        else        ((u16*)Cv)[idx]   = f2b(val);
      }
    }
  }
}

template<bool F32OUT>
__global__ __launch_bounds__(256,2) void gemm_bt(
    const u16* __restrict__ A, const u16* __restrict__ Bt, const float* __restrict__ bias,
    float bscale, void* __restrict__ Cv, int N, int K, long sA, long sB, long sC, int bias_on_m)
{
  __shared__ __align__(16) u16 As[128*64];
  __shared__ __align__(16) u16 Bs[128*64];
  const int z = blockIdx.z;
  gemm_core<F32OUT>(A + (size_t)z*sA, Bt + (size_t)z*sB, bias, bscale, Cv, (size_t)z*sC,
                    N, K, bias_on_m, blockIdx.y*128, blockIdx.x*128, As, Bs);
}

// fused Q+K projection: z = b + 2*sel
__global__ __launch_bounds__(256,2) void gemm_qk(
    const u16* __restrict__ qT, const u16* __restrict__ kT,
    const u16* __restrict__ Wq16, const u16* __restrict__ Wk16,
    const float* __restrict__ bq, const float* __restrict__ bk,
    u16* __restrict__ Qb, u16* __restrict__ Kb)
{
  __shared__ __align__(16) u16 As[128*64];
  __shared__ __align__(16) u16 Bs[128*64];
  const int z = blockIdx.z, b = z&1, sel = z>>1;
  const size_t sSE = (size_t)2048*1024;
  gemm_core<false>((sel? kT : qT) + b*sSE, sel? Wk16 : Wq16, sel? bk : bq,
                   sel? 1.0f : 0.125f, sel? Kb : Qb, b*sSE,
                   1024, 1024, 0, blockIdx.y*128, blockIdx.x*128, As, Bs);
}

// ---------------- fused flash attention per (b, h, 128-q tile) ----------------------------
// Qb/Kb: bf16 [b][s][h*64+d] (Q pre-scaled by 0.125)  Vb: bf16 [b][h*64+c][s]
// classes: [b][32][32] per-64x64 tile  Ot: bf16 [b][s][h*64+c]
__global__ __launch_bounds__(256,1) void attn(
    const u16* __restrict__ Qb, const u16* __restrict__ Kb, const u16* __restrict__ Vb,
    const float* __restrict__ qk_mask, const float* __restrict__ k_mask,
    const char* __restrict__ classes, u16* __restrict__ Ot)
{
  __shared__ __align__(16) u16 Qs[128*64];
  __shared__ __align__(16) u16 Ks[128*64];
  __shared__ __align__(16) u16 Vs[64*128];
  __shared__ __align__(16) u16 Ps[4][16*128];
  const int h = blockIdx.y, b = blockIdx.z;
  const int qt = (b==0) ? (int)blockIdx.x : 15 - (int)blockIdx.x;  // load-balance causal tail
  const int tid = threadIdx.x, w = tid>>6, lane = tid&63;
  const int ln = lane&15, quad = lane>>4;
  const int S = 2048;
  const int q0 = qt*128;

  stage128x64_sw(Qb + ((size_t)b*S + q0)*1024 + h*64, Qs, 1024, w, lane);

  const char* cl0 = classes + ((size_t)b*32 + qt*2)*32;

  float m_run[2][4], l_run[2][4];
  f32x4 acc_o[2][4];
  #pragma unroll
  for(int mt=0;mt<2;++mt){
    #pragma unroll
    for(int r=0;r<4;++r){ m_run[mt][r] = -1e30f; l_run[mt][r] = 0.f; }
    #pragma unroll
    for(int ct=0;ct<4;++ct) acc_o[mt][ct] = f32x4{0.f,0.f,0.f,0.f};
  }

  for (int kt=0; kt<16; ++kt){
    const char c00 = cl0[kt*2], c01 = cl0[kt*2+1], c10 = cl0[32+kt*2], c11 = cl0[32+kt*2+1];
    if (c00==2 && c01==2 && c10==2 && c11==2) continue;      // fully masked: exact skip
    const bool nomask = (c00|c01|c10|c11)==0;
    const int k0 = kt*128;
    __syncthreads();
    stage128x64_sw(Kb + ((size_t)b*S + k0)*1024 + h*64, Ks, 1024, w, lane);
    stage64x128_sw(Vb + ((size_t)b*1024 + h*64)*S + k0, Vs, S, w, lane);
    __syncthreads();

    // S-tile: q rows (wave owns 32), k cols (128)
    f32x4 sa[2][8];
    #pragma unroll
    for(int mt=0;mt<2;++mt)
      #pragma unroll
      for(int nt=0;nt<8;++nt) sa[mt][nt] = f32x4{0.f,0.f,0.f,0.f};
    #pragma unroll
    for (int kk=0; kk<64; kk+=32){
      const int c16 = (kk>>3) + quad;
      short8 af[2], bf[8];
      #pragma unroll
      for (int mt=0;mt<2;++mt) af[mt] = *frag64(Qs, w*32+mt*16+ln, c16);
      #pragma unroll
      for (int nt=0;nt<8;++nt) bf[nt] = *frag64(Ks, nt*16+ln, c16);
      #pragma unroll
      for (int mt=0;mt<2;++mt)
        #pragma unroll
        for (int nt=0;nt<8;++nt)
          sa[mt][nt] = MFMA16(af[mt], bf[nt], sa[mt][nt]);
    }
    if (!nomask){
      float kmv[8];
      #pragma unroll
      for (int nt=0;nt<8;++nt) kmv[nt] = k_mask[(size_t)b*S + k0 + nt*16 + ln];
      #pragma unroll
      for (int mt=0;mt<2;++mt){
        #pragma unroll
        for (int nt=0;nt<8;++nt){
          const size_t mbase = ((size_t)b*S + (size_t)(k0+nt*16+ln))*S + q0 + w*32 + mt*16 + quad*4;
          const float4 mq = *(const float4*)&qk_mask[mbase];
          sa[mt][nt][0] += mq.x + kmv[nt];
          sa[mt][nt][1] += mq.y + kmv[nt];
          sa[mt][nt][2] += mq.z + kmv[nt];
          sa[mt][nt][3] += mq.w + kmv[nt];
        }
      }
    }
    // per mt-half: online softmax + swizzled P write + PV MFMA
    #pragma unroll
    for (int mt=0;mt<2;++mt){
      #pragma unroll
      for (int r=0;r<4;++r){
        float mx = sa[mt][0][r];
        #pragma unroll
        for (int nt=1;nt<8;++nt) mx = fmaxf(mx, sa[mt][nt][r]);
        #pragma unroll
        for (int d=1; d<16; d<<=1) mx = fmaxf(mx, __shfl_xor(mx, d, 64));
        const float nm = fmaxf(m_run[mt][r], mx);
        const float alpha = __expf(m_run[mt][r] - nm);
        m_run[mt][r] = nm;
        const int rq = quad*4 + r;
        float rs = 0.f;
        #pragma unroll
        for (int nt=0;nt<8;++nt){
          const float p = __expf(sa[mt][nt][r] - nm);
          rs += p;
          const int u = (nt*2 + (ln>>3)) ^ (rq&7);
          Ps[w][rq*128 + (u<<3) + (ln&7)] = f2b(p);
        }
        #pragma unroll
        for (int d=1; d<16; d<<=1) rs += __shfl_xor(rs, d, 64);
        l_run[mt][r] = l_run[mt][r]*alpha + rs;
        #pragma unroll
        for (int ct=0;ct<4;++ct) acc_o[mt][ct][r] *= alpha;
      }
      #pragma unroll
      for (int kk=0; kk<128; kk+=32){
        const int c16 = (kk>>3) + quad;
        short8 pf, vf[4];
        pf = *(const short8*)&Ps[w][ln*128 + (((c16) ^ (ln&7))<<3)];
        #pragma unroll
        for (int ct=0;ct<4;++ct) vf[ct] = *frag128(Vs, ct*16+ln, c16);
        #pragma unroll
        for (int ct=0;ct<4;++ct)
          acc_o[mt][ct] = MFMA16(pf, vf[ct], acc_o[mt][ct]);
      }
    }
  }
  // epilogue
  #pragma unroll
  for (int mt=0;mt<2;++mt){
    #pragma unroll
    for (int ct=0;ct<4;++ct){
      #pragma unroll
      for (int r=0;r<4;++r){
        const float o = acc_o[mt][ct][r] / l_run[mt][r];
        Ot[((size_t)b*S + q0 + w*32 + mt*16 + quad*4 + r)*1024 + h*64 + ct*16 + ln] = f2b(o);
      }
    }
  }
}

extern "C" void kernel_launch(void* const* d_in, const int* in_sizes, int n_in,
                              void* d_out, int out_size, void* d_ws, size_t ws_size,
                              hipStream_t stream)
{
  const float* q   = (const float*)d_in[0];
  const float* k   = (const float*)d_in[1];
  const float* v   = (const float*)d_in[2];
  const float* qkm = (const float*)d_in[3];
  const float* km  = (const float*)d_in[4];
  const float* Wq  = (const float*)d_in[5];
  const float* bq  = (const float*)d_in[6];
  const float* Wk  = (const float*)d_in[7];
  const float* bk  = (const float*)d_in[8];
  const float* Wv  = (const float*)d_in[9];
  const float* bv  = (const float*)d_in[10];
  const float* Wo  = (const float*)d_in[11];
  const float* bo  = (const float*)d_in[12];
  float* out = (float*)d_out;

  const int B=2, S=2048, E=1024;
  const long sSE = (long)S*E;
  const size_t nAct = (size_t)B*S*E;     // 4M elems
  const int   nW   = E*E;                // 1M elems

  u16* A0 = (u16*)d_ws;          // qT, later vT
  u16* A1 = A0 + nAct;           // kT, later attnT
  u16* A2 = A1 + nAct;           // Qb
  u16* A3 = A2 + nAct;           // Kb
  u16* A4 = A3 + nAct;           // Vb
  u16* W16 = A4 + nAct;          // Wq16|Wk16|Wv16|Wo16
  char* classes = (char*)(W16 + (size_t)4*nW);   // 2 KB
  u16* Wq16 = W16, *Wk16 = W16+nW, *Wv16 = W16+2*(size_t)nW, *Wo16 = W16+3*(size_t)nW;

  dim3 blk(256);
  cvt_w     <<<dim3(nW/(256*8), 4), blk, 0, stream>>>(Wq, Wk, Wv, Wo, W16, nW);
  maskclass <<<dim3(32, 32, B),     blk, 0, stream>>>(qkm, km, classes);
  transp_cvt2<<<dim3(S/64, E/64, 2*B), blk, 0, stream>>>(q, k, A0, A1, E, S, B);
  gemm_qk   <<<dim3(E/128, S/128, 2*B), blk, 0, stream>>>(A0, A1, Wq16, Wk16, bq, bk, A2, A3);
  transp_cvt2<<<dim3(S/64, E/64, B), blk, 0, stream>>>(v, v, A0, A0, E, S, B);
  gemm_bt<false><<<dim3(S/128, E/128, B), blk, 0, stream>>>(Wv16, A0, bv, 1.0f, A4, S, E, 0, sSE, sSE, 1);
  attn      <<<dim3(S/128, 16, B), blk, 0, stream>>>(A2, A3, A4, qkm, km, classes, A1);
  gemm_bt<true><<<dim3(S/128, E/128, B), blk, 0, stream>>>(Wo16, A1, bo, 1.0f, out, S, E, 0, sSE, sSE, 1);
}

// Round 5
// 288.425 us; speedup vs baseline: 1.7914x; 1.1994x over previous
//
#include <hip/hip_runtime.h>
#include <hip/hip_bf16.h>
#include <stdint.h>

typedef unsigned short u16;
typedef __attribute__((ext_vector_type(8))) short short8;
typedef __attribute__((ext_vector_type(4))) short short4v;
typedef __attribute__((ext_vector_type(4))) float f32x4;

#define MFMA16(a,b,c) __builtin_amdgcn_mfma_f32_16x16x32_bf16((a),(b),(c),0,0,0)
#define EXP2F(x) __builtin_amdgcn_exp2f(x)

typedef const __attribute__((address_space(1))) void glb_void;
typedef __attribute__((address_space(3))) void lds_void;

__device__ __forceinline__ u16 f2b(float f){
  unsigned u = __float_as_uint(f);
  u += 0x7fffu + ((u>>16)&1u);
  return (u16)(u>>16);
}
__device__ __forceinline__ unsigned pack_bf16(float a, float b){
  __hip_bfloat162 h = __float22bfloat162_rn(make_float2(a,b));
  unsigned u; __builtin_memcpy(&u, &h, 4); return u;
}
__device__ __forceinline__ void gld16(const void* g, void* l){
  __builtin_amdgcn_global_load_lds((glb_void*)g, (lds_void*)l, 16, 0, 0);
}

// ---- swizzled staging: LDS[row][c] = G[row][ (c/8 ^ (row&7))*8 + c%8 ]  (128 rows x 64) ----
__device__ __forceinline__ void stage128x64_sw(const u16* g, u16* lds, int gstride, int w, int lane){
  const int sub = lane>>3, c16 = lane&7;
  const int gcol = (c16 ^ sub)<<3;
  #pragma unroll
  for (int i=0;i<4;++i){
    int r0 = (w*4+i)*8;
    gld16(g + (size_t)(r0 + sub)*gstride + gcol, lds + r0*64);
  }
}
__device__ __forceinline__ const short8* frag64(const u16* lds, int row, int c16){
  return (const short8*)(lds + row*64 + ((c16 ^ (row&7))<<3));
}
// ---- 64 rows x 128, swizzle on row&15 ----
__device__ __forceinline__ void stage64x128_sw(const u16* g, u16* lds, int gstride, int w, int lane){
  const int sub = lane>>4, c16 = lane&15;
  #pragma unroll
  for (int i=0;i<4;++i){
    int r0 = (w*4+i)*4;
    int row = r0 + sub;
    gld16(g + (size_t)row*gstride + ((c16 ^ (row&15))<<3), lds + r0*128);
  }
}
__device__ __forceinline__ const short8* frag128(const u16* lds, int row, int c16){
  return (const short8*)(lds + row*128 + ((c16 ^ (row&15))<<3));
}

// ---------------- weights f32 -> bf16 (Wq pre-scaled by 0.125*log2e) ----------------------
__global__ __launch_bounds__(256) void cvt_w(const float* __restrict__ Wq, const float* __restrict__ Wk,
                                             const float* __restrict__ Wv, const float* __restrict__ Wo,
                                             u16* __restrict__ o16, int nW){
  const int sel = blockIdx.y;
  const float* src = sel==0?Wq : sel==1?Wk : sel==2?Wv : Wo;
  const float sc = (sel==0) ? 0.18033688f : 1.0f;   // 0.125 * log2(e)
  u16* dst = o16 + (size_t)sel*nW;
  int i = (blockIdx.x*256 + threadIdx.x)*8;
  if (i >= nW) return;
  float4 a = *(const float4*)(src+i);
  float4 b = *(const float4*)(src+i+4);
  short8 o;
  o[0]=(short)f2b(a.x*sc); o[1]=(short)f2b(a.y*sc); o[2]=(short)f2b(a.z*sc); o[3]=(short)f2b(a.w*sc);
  o[4]=(short)f2b(b.x*sc); o[5]=(short)f2b(b.y*sc); o[6]=(short)f2b(b.z*sc); o[7]=(short)f2b(b.w*sc);
  *(short8*)(dst+i) = o;
}

// ---------------- mask tile classification (64x64): 0=all zero, 1=mixed, 2=all masked -----
__global__ __launch_bounds__(256) void maskclass(const float* __restrict__ qkm, const float* __restrict__ km,
                                                 char* __restrict__ classes){
  __shared__ int az_s, an_s;
  const int b = blockIdx.z, ki = blockIdx.x, qi = blockIdx.y;
  const int k0 = ki*64, q0 = qi*64;
  const int tid = threadIdx.x;
  if (tid==0){ az_s = 1; an_s = 1; }
  __syncthreads();
  int az = 1, an = 1;
  #pragma unroll
  for (int p=0;p<4;++p){
    int e = tid + p*256;
    int row = e>>4, c4 = (e&15)*4;
    float kmv = km[(size_t)b*2048 + k0 + row];
    float4 v = *(const float4*)&qkm[((size_t)b*2048 + k0 + row)*2048 + q0 + c4];
    v.x += kmv; v.y += kmv; v.z += kmv; v.w += kmv;
    az &= (v.x==0.f) & (v.y==0.f) & (v.z==0.f) & (v.w==0.f);
    an &= (v.x<-1e3f) & (v.y<-1e3f) & (v.z<-1e3f) & (v.w<-1e3f);
  }
  if (!az) atomicAnd(&az_s, 0);
  if (!an) atomicAnd(&an_s, 0);
  __syncthreads();
  if (tid==0){
    char c = an_s ? 2 : (az_s ? 0 : 1);
    classes[((size_t)b*32 + qi)*32 + ki] = c;
  }
}

// ---------------- transpose+convert: x_f32[b][Cdim][Sdim] -> xt_bf16[b][Sdim][Cdim] -------
__global__ __launch_bounds__(256) void transp_cvt2(const float* __restrict__ x0, const float* __restrict__ x1,
                                                   u16* __restrict__ y0, u16* __restrict__ y1,
                                                   int Cdim, int Sdim, int nb){
  __shared__ __align__(16) float t[64][72];
  const int z = blockIdx.z, b = z % nb, sel = z / nb;
  const float* x = sel ? x1 : x0;
  u16* xt = sel ? y1 : y0;
  const int c0 = blockIdx.y*64, s0 = blockIdx.x*64;
  const int tid = threadIdx.x;
  #pragma unroll
  for (int p=0;p<4;++p){
    int e = tid + p*256;
    int row = e>>4, c4 = (e&15)*4;
    *(float4*)&t[row][c4] = *(const float4*)&x[((size_t)b*Cdim + c0 + row)*Sdim + s0 + c4];
  }
  __syncthreads();
  #pragma unroll
  for (int p=0;p<2;++p){
    int e = tid + p*256;
    int row = e>>3, col8 = (e&7)*8;
    short8 o;
    #pragma unroll
    for (int u=0;u<8;++u) o[u] = (short)f2b(t[col8+u][row]);
    *(short8*)&xt[((size_t)b*Sdim + s0 + row)*Cdim + c0 + col8] = o;
  }
}

// ---------------- GEMM core: C[M][N] = A[M][K]*Bt[N][K]^T + bias*bscale -------------------
template<bool F32OUT>
__device__ __forceinline__ void gemm_core(
    const u16* __restrict__ A, const u16* __restrict__ Bt, const float* __restrict__ bias,
    float bscale, void* __restrict__ Cv, size_t cbase, int N, int K, int bias_on_m,
    int m0, int n0, u16* As, u16* Bs)
{
  const int tid = threadIdx.x, w = tid>>6, lane = tid&63;
  const int ln = lane&15, quad = lane>>4;
  const int m0w = (w>>1)*64, n0w = (w&1)*64;
  f32x4 acc[4][4];
  #pragma unroll
  for(int i=0;i<4;++i)
    #pragma unroll
    for(int j=0;j<4;++j) acc[i][j] = f32x4{0.f,0.f,0.f,0.f};

  for (int kc=0; kc<K; kc+=64){
    __syncthreads();
    stage128x64_sw(A  + (size_t)m0*K + kc, As, K, w, lane);
    stage128x64_sw(Bt + (size_t)n0*K + kc, Bs, K, w, lane);
    __syncthreads();
    #pragma unroll
    for (int kk=0; kk<64; kk+=32){
      const int c16 = (kk>>3) + quad;
      short8 af[4], bf[4];
      #pragma unroll
      for (int mt=0;mt<4;++mt) af[mt] = *frag64(As, m0w+mt*16+ln, c16);
      #pragma unroll
      for (int nt=0;nt<4;++nt) bf[nt] = *frag64(Bs, n0w+nt*16+ln, c16);
      #pragma unroll
      for (int mt=0;mt<4;++mt)
        #pragma unroll
        for (int nt=0;nt<4;++nt)
          acc[mt][nt] = MFMA16(af[mt], bf[nt], acc[mt][nt]);
    }
  }
  #pragma unroll
  for (int mt=0;mt<4;++mt){
    #pragma unroll
    for (int nt=0;nt<4;++nt){
      const int col = n0 + n0w + nt*16 + ln;
      const float bn = bias_on_m ? 0.f : bias[col]*bscale;
      #pragma unroll
      for (int r=0;r<4;++r){
        const int row = m0 + m0w + mt*16 + quad*4 + r;
        const float bb = bias_on_m ? bias[row]*bscale : bn;
        const float val = acc[mt][nt][r] + bb;
        const size_t idx = cbase + (size_t)row*N + col;
        if (F32OUT) ((float*)Cv)[idx] = val;
        else        ((u16*)Cv)[idx]   = f2b(val);
      }
    }
  }
}

template<bool F32OUT>
__global__ __launch_bounds__(256,3) void gemm_bt(
    const u16* __restrict__ A, const u16* __restrict__ Bt, const float* __restrict__ bias,
    float bscale, void* __restrict__ Cv, int N, int K, long sA, long sB, long sC, int bias_on_m)
{
  __shared__ __align__(16) u16 As[128*64];
  __shared__ __align__(16) u16 Bs[128*64];
  const int z = blockIdx.z;
  gemm_core<F32OUT>(A + (size_t)z*sA, Bt + (size_t)z*sB, bias, bscale, Cv, (size_t)z*sC,
                    N, K, bias_on_m, blockIdx.y*128, blockIdx.x*128, As, Bs);
}

// fused Q+K projection: z = b + 2*sel
__global__ __launch_bounds__(256,3) void gemm_qk(
    const u16* __restrict__ qT, const u16* __restrict__ kT,
    const u16* __restrict__ Wq16, const u16* __restrict__ Wk16,
    const float* __restrict__ bq, const float* __restrict__ bk,
    u16* __restrict__ Qb, u16* __restrict__ Kb)
{
  __shared__ __align__(16) u16 As[128*64];
  __shared__ __align__(16) u16 Bs[128*64];
  const int z = blockIdx.z, b = z&1, sel = z>>1;
  const size_t sSE = (size_t)2048*1024;
  gemm_core<false>((sel? kT : qT) + b*sSE, sel? Wk16 : Wq16, sel? bk : bq,
                   sel? 1.0f : 0.18033688f, sel? Kb : Qb, b*sSE,
                   1024, 1024, 0, blockIdx.y*128, blockIdx.x*128, As, Bs);
}

// ---------------- fused flash attention, uniform-work blocks ------------------------------
// Qb: bf16 [b][s][h*64+d] pre-scaled by 0.125*log2e; Kb unscaled; Vb: bf16 [b][h*64+c][s]
// Block = (b, h, pair p, half): processes q-subtiles (15-p, half) then (p, half), 64 q-rows each.
// S^T = K*Q^T per 128k-tile; fixed-offset exp2 softmax (no max, no rescale); P to PV B-operand
// via in-register quad shuffles; O^T accumulated in C-layout; l reduced once at epilogue.
__global__ __launch_bounds__(256,2) void attn(
    const u16* __restrict__ Qb, const u16* __restrict__ Kb, const u16* __restrict__ Vb,
    const float* __restrict__ qk_mask, const float* __restrict__ k_mask,
    const char* __restrict__ classes, u16* __restrict__ Ot)
{
  __shared__ __align__(16) u16 Ks[128*64];
  __shared__ __align__(16) u16 Vs[64*128];
  const int x = blockIdx.x;
  const int b = x&1, h = (x>>1)&15;
  const int pp = x>>5, pair = pp>>1, half = pp&1;
  const int tid = threadIdx.x, w = tid>>6, lane = tid&63;
  const int ln = lane&15, quad = lane>>4;
  const int S = 2048;
  const float LOG2E = 1.44269504f, C2 = 16.0f;

  #pragma unroll
  for (int sub=0; sub<2; ++sub){
    const int qt = sub ? pair : (15-pair);
    const int qbase = qt*128 + half*64;
    const int qg = qbase + w*16 + ln;           // this lane's q column
    // Q B-operand fragments (registers, one load per sub-tile)
    short8 qf[2];
    #pragma unroll
    for (int kkI=0;kkI<2;++kkI)
      qf[kkI] = *(const short8*)&Qb[((size_t)b*S + qg)*1024 + h*64 + kkI*32 + quad*8];

    const char* cl = classes + ((size_t)b*32 + qt*2 + half)*32;
    float rs = 0.f;
    f32x4 acc[4];
    #pragma unroll
    for (int ct=0;ct<4;++ct) acc[ct] = f32x4{0.f,0.f,0.f,0.f};

    for (int kt=0; kt<16; ++kt){
      const char c0 = cl[2*kt], c1 = cl[2*kt+1];
      if (c0==2 && c1==2) continue;             // fully masked: exact skip
      const bool nomask = (c0|c1)==0;
      const int k0 = kt*128;
      __syncthreads();
      stage128x64_sw(Kb + ((size_t)b*S + k0)*1024 + h*64, Ks, 1024, w, lane);
      stage64x128_sw(Vb + ((size_t)b*1024 + h*64)*S + k0, Vs, S, w, lane);
      __syncthreads();

      // S^T tiles: m=k (8 tiles of 16), n=q (16 per wave); then exp2, pack
      unsigned pk[8][2];
      #pragma unroll
      for (int t=0;t<8;++t){
        f32x4 s = f32x4{0.f,0.f,0.f,0.f};
        #pragma unroll
        for (int kkI=0;kkI<2;++kkI)
          s = MFMA16(*frag64(Ks, t*16+ln, kkI*4 + quad), qf[kkI], s);
        float e[4];
        if (nomask){
          #pragma unroll
          for (int r=0;r<4;++r) e[r] = EXP2F(s[r] - C2);
        } else {
          #pragma unroll
          for (int r=0;r<4;++r){
            const int kg = k0 + t*16 + quad*4 + r;
            const float m = qk_mask[((size_t)b*S + kg)*S + qg] + k_mask[(size_t)b*S + kg];
            e[r] = EXP2F(fmaf(m, LOG2E, s[r]) - C2);
          }
        }
        rs += (e[0]+e[1]) + (e[2]+e[3]);
        pk[t][0] = pack_bf16(e[0], e[1]);
        pk[t][1] = pack_bf16(e[2], e[3]);
      }
      // PV: O^T[c][q] += V[c][k] * P[k][q];  B-frag built by quad shuffle
      const int srcA = (quad&1)*32 + ln, srcB = srcA + 16;
      const bool hi = (quad>>1)&1;
      #pragma unroll
      for (int c=0;c<4;++c){
        unsigned a0 = __shfl((int)pk[2*c][0],   srcA, 64);
        unsigned a1 = __shfl((int)pk[2*c][1],   srcA, 64);
        unsigned a2 = __shfl((int)pk[2*c][0],   srcB, 64);
        unsigned a3 = __shfl((int)pk[2*c][1],   srcB, 64);
        unsigned b0 = __shfl((int)pk[2*c+1][0], srcA, 64);
        unsigned b1 = __shfl((int)pk[2*c+1][1], srcA, 64);
        unsigned b2 = __shfl((int)pk[2*c+1][0], srcB, 64);
        unsigned b3 = __shfl((int)pk[2*c+1][1], srcB, 64);
        short8 pf;
        ((unsigned*)&pf)[0] = hi ? b0 : a0;
        ((unsigned*)&pf)[1] = hi ? b1 : a1;
        ((unsigned*)&pf)[2] = hi ? b2 : a2;
        ((unsigned*)&pf)[3] = hi ? b3 : a3;
        #pragma unroll
        for (int ct=0;ct<4;++ct)
          acc[ct] = MFMA16(*frag128(Vs, ct*16+ln, c*4 + quad), pf, acc[ct]);
      }
    }
    // epilogue: l = sum over quads; O = acc / l
    rs += __shfl_xor(rs, 16, 64);
    rs += __shfl_xor(rs, 32, 64);
    const float rinv = 1.0f / rs;
    #pragma unroll
    for (int ct=0;ct<4;++ct){
      short4v o4;
      #pragma unroll
      for (int r=0;r<4;++r) o4[r] = (short)f2b(acc[ct][r] * rinv);
      *(short4v*)&Ot[((size_t)b*S + qg)*1024 + h*64 + ct*16 + quad*4] = o4;
    }
  }
}

extern "C" void kernel_launch(void* const* d_in, const int* in_sizes, int n_in,
                              void* d_out, int out_size, void* d_ws, size_t ws_size,
                              hipStream_t stream)
{
  const float* q   = (const float*)d_in[0];
  const float* k   = (const float*)d_in[1];
  const float* v   = (const float*)d_in[2];
  const float* qkm = (const float*)d_in[3];
  const float* km  = (const float*)d_in[4];
  const float* Wq  = (const float*)d_in[5];
  const float* bq  = (const float*)d_in[6];
  const float* Wk  = (const float*)d_in[7];
  const float* bk  = (const float*)d_in[8];
  const float* Wv  = (const float*)d_in[9];
  const float* bv  = (const float*)d_in[10];
  const float* Wo  = (const float*)d_in[11];
  const float* bo  = (const float*)d_in[12];
  float* out = (float*)d_out;

  const int B=2, S=2048, E=1024;
  const long sSE = (long)S*E;
  const size_t nAct = (size_t)B*S*E;     // 4M elems
  const int   nW   = E*E;                // 1M elems

  u16* A0 = (u16*)d_ws;          // qT, later vT
  u16* A1 = A0 + nAct;           // kT, later attnT
  u16* A2 = A1 + nAct;           // Qb
  u16* A3 = A2 + nAct;           // Kb
  u16* A4 = A3 + nAct;           // Vb
  u16* W16 = A4 + nAct;          // Wq16|Wk16|Wv16|Wo16
  char* classes = (char*)(W16 + (size_t)4*nW);   // 2 KB
  u16* Wq16 = W16, *Wk16 = W16+nW, *Wv16 = W16+2*(size_t)nW, *Wo16 = W16+3*(size_t)nW;

  dim3 blk(256);
  cvt_w     <<<dim3(nW/(256*8), 4), blk, 0, stream>>>(Wq, Wk, Wv, Wo, W16, nW);
  maskclass <<<dim3(32, 32, B),     blk, 0, stream>>>(qkm, km, classes);
  transp_cvt2<<<dim3(S/64, E/64, 2*B), blk, 0, stream>>>(q, k, A0, A1, E, S, B);
  gemm_qk   <<<dim3(E/128, S/128, 2*B), blk, 0, stream>>>(A0, A1, Wq16, Wk16, bq, bk, A2, A3);
  transp_cvt2<<<dim3(S/64, E/64, B), blk, 0, stream>>>(v, v, A0, A0, E, S, B);
  gemm_bt<false><<<dim3(S/128, E/128, B), blk, 0, stream>>>(Wv16, A0, bv, 1.0f, A4, S, E, 0, sSE, sSE, 1);
  attn      <<<dim3(512), blk, 0, stream>>>(A2, A3, A4, qkm, km, classes, A1);
  gemm_bt<true><<<dim3(S/128, E/128, B), blk, 0, stream>>>(Wo16, A1, bo, 1.0f, out, S, E, 0, sSE, sSE, 1);
}

// Round 6
// 254.688 us; speedup vs baseline: 2.0287x; 1.1325x over previous
//
#include <hip/hip_runtime.h>
#include <hip/hip_bf16.h>
#include <stdint.h>

typedef unsigned short u16;
typedef __attribute__((ext_vector_type(8))) short short8;
typedef __attribute__((ext_vector_type(4))) short short4v;
typedef __attribute__((ext_vector_type(4))) float f32x4;

#define MFMA16(a,b,c) __builtin_amdgcn_mfma_f32_16x16x32_bf16((a),(b),(c),0,0,0)
#define EXP2F(x) __builtin_amdgcn_exp2f(x)

typedef const __attribute__((address_space(1))) void glb_void;
typedef __attribute__((address_space(3))) void lds_void;

__device__ __forceinline__ u16 f2b(float f){
  unsigned u = __float_as_uint(f);
  u += 0x7fffu + ((u>>16)&1u);
  return (u16)(u>>16);
}
__device__ __forceinline__ unsigned pack_bf16(float a, float b){
  __hip_bfloat162 h = __float22bfloat162_rn(make_float2(a,b));
  unsigned u; __builtin_memcpy(&u, &h, 4); return u;
}
__device__ __forceinline__ void gld16(const void* g, void* l){
  __builtin_amdgcn_global_load_lds((glb_void*)g, (lds_void*)l, 16, 0, 0);
}

// ---- swizzled staging: LDS[row][c] = G[row][ (c/8 ^ (row&7))*8 + c%8 ] ----
__device__ __forceinline__ void stage128x64_sw(const u16* g, u16* lds, int gstride, int w, int lane){
  const int sub = lane>>3, c16 = lane&7;
  const int gcol = (c16 ^ sub)<<3;
  #pragma unroll
  for (int i=0;i<4;++i){
    int r0 = (w*4+i)*8;
    gld16(g + (size_t)(r0 + sub)*gstride + gcol, lds + r0*64);
  }
}
__device__ __forceinline__ void stage64x64_sw(const u16* g, u16* lds, int gstride, int w, int lane){
  const int sub = lane>>3, c16 = lane&7;
  const int gcol = (c16 ^ sub)<<3;
  #pragma unroll
  for (int i=0;i<2;++i){
    int r0 = (w*2+i)*8;
    gld16(g + (size_t)(r0 + sub)*gstride + gcol, lds + r0*64);
  }
}
__device__ __forceinline__ const short8* frag64(const u16* lds, int row, int c16){
  return (const short8*)(lds + row*64 + ((c16 ^ (row&7))<<3));
}
__device__ __forceinline__ void stage64x128_sw(const u16* g, u16* lds, int gstride, int w, int lane){
  const int sub = lane>>4, c16 = lane&15;
  #pragma unroll
  for (int i=0;i<4;++i){
    int r0 = (w*4+i)*4;
    int row = r0 + sub;
    gld16(g + (size_t)row*gstride + ((c16 ^ (row&15))<<3), lds + r0*128);
  }
}
__device__ __forceinline__ const short8* frag128(const u16* lds, int row, int c16){
  return (const short8*)(lds + row*128 + ((c16 ^ (row&15))<<3));
}

// ================= PREP: weight cvt + mask classes + q/k/v transposes, one dispatch =======
// blocks [0,2048): cvt_w ; [2048,4096): maskclass ; [4096,7168): transp q/k/v
__global__ __launch_bounds__(256) void prep(
    const float* __restrict__ q, const float* __restrict__ k, const float* __restrict__ v,
    const float* __restrict__ qkm, const float* __restrict__ km,
    const float* __restrict__ Wq, const float* __restrict__ Wk,
    const float* __restrict__ Wv, const float* __restrict__ Wo,
    u16* __restrict__ W16, char* __restrict__ classes,
    u16* __restrict__ qT, u16* __restrict__ kT, u16* __restrict__ vT)
{
  __shared__ __align__(16) float t[64][72];
  const int bx = blockIdx.x, tid = threadIdx.x;
  const int S = 2048, E = 1024, nW = E*E;

  if (bx < 2048){                      // ---- weight convert ----
    const int sel = bx>>9, blk = bx&511;
    const float* src = sel==0?Wq : sel==1?Wk : sel==2?Wv : Wo;
    const float sc = (sel==0) ? 0.18033688f : 1.0f;   // 0.125 * log2(e)
    u16* dst = W16 + (size_t)sel*nW;
    int i = (blk*256 + tid)*8;
    float4 a = *(const float4*)(src+i);
    float4 b = *(const float4*)(src+i+4);
    short8 o;
    o[0]=(short)f2b(a.x*sc); o[1]=(short)f2b(a.y*sc); o[2]=(short)f2b(a.z*sc); o[3]=(short)f2b(a.w*sc);
    o[4]=(short)f2b(b.x*sc); o[5]=(short)f2b(b.y*sc); o[6]=(short)f2b(b.z*sc); o[7]=(short)f2b(b.w*sc);
    *(short8*)(dst+i) = o;
  } else if (bx < 4096){               // ---- mask tile classification (64x64) ----
    const int tt = bx - 2048;
    const int b = tt>>10, qi = (tt>>5)&31, ki = tt&31;
    const int k0 = ki*64, q0 = qi*64;
    int az = 1, an = 1;
    #pragma unroll
    for (int p=0;p<4;++p){
      int e = tid + p*256;
      int row = e>>4, c4 = (e&15)*4;
      float kmv = km[(size_t)b*S + k0 + row];
      float4 mv = *(const float4*)&qkm[((size_t)b*S + k0 + row)*S + q0 + c4];
      mv.x += kmv; mv.y += kmv; mv.z += kmv; mv.w += kmv;
      az &= (mv.x==0.f) & (mv.y==0.f) & (mv.z==0.f) & (mv.w==0.f);
      an &= (mv.x<-1e3f) & (mv.y<-1e3f) & (mv.z<-1e3f) & (mv.w<-1e3f);
    }
    const int az_all = __syncthreads_and(az);
    const int an_all = __syncthreads_and(an);
    if (tid==0)
      classes[((size_t)b*32 + qi)*32 + ki] = an_all ? 2 : (az_all ? 0 : 1);
  } else {                             // ---- transpose+convert q/k/v ----
    const int tt = bx - 4096;
    const int tensor = tt>>10, r = tt&1023;
    const int b = r>>9, rr = r&511;
    const int c0 = (rr>>5)*64, s0 = (rr&31)*64;
    const float* x = tensor==0 ? q : tensor==1 ? k : v;
    u16* xt = tensor==0 ? qT : tensor==1 ? kT : vT;
    #pragma unroll
    for (int p=0;p<4;++p){
      int e = tid + p*256;
      int row = e>>4, c4 = (e&15)*4;
      *(float4*)&t[row][c4] = *(const float4*)&x[((size_t)b*E + c0 + row)*S + s0 + c4];
    }
    __syncthreads();
    #pragma unroll
    for (int p=0;p<2;++p){
      int e = tid + p*256;
      int row = e>>3, col8 = (e&7)*8;
      short8 o;
      #pragma unroll
      for (int u=0;u<8;++u) o[u] = (short)f2b(t[col8+u][row]);
      *(short8*)&xt[((size_t)b*S + s0 + row)*E + c0 + col8] = o;
    }
  }
}

// ---------------- GEMM core: C[M][N] = A[M][K]*Bt[N][K]^T + bias*bscale -------------------
template<bool F32OUT>
__device__ __forceinline__ void gemm_core(
    const u16* __restrict__ A, const u16* __restrict__ Bt, const float* __restrict__ bias,
    float bscale, void* __restrict__ Cv, size_t cbase, int N, int K, int bias_on_m,
    int m0, int n0, u16* As, u16* Bs)
{
  const int tid = threadIdx.x, w = tid>>6, lane = tid&63;
  const int ln = lane&15, quad = lane>>4;
  const int m0w = (w>>1)*64, n0w = (w&1)*64;
  f32x4 acc[4][4];
  #pragma unroll
  for(int i=0;i<4;++i)
    #pragma unroll
    for(int j=0;j<4;++j) acc[i][j] = f32x4{0.f,0.f,0.f,0.f};

  for (int kc=0; kc<K; kc+=64){
    __syncthreads();
    stage128x64_sw(A  + (size_t)m0*K + kc, As, K, w, lane);
    stage128x64_sw(Bt + (size_t)n0*K + kc, Bs, K, w, lane);
    __syncthreads();
    #pragma unroll
    for (int kk=0; kk<64; kk+=32){
      const int c16 = (kk>>3) + quad;
      short8 af[4], bf[4];
      #pragma unroll
      for (int mt=0;mt<4;++mt) af[mt] = *frag64(As, m0w+mt*16+ln, c16);
      #pragma unroll
      for (int nt=0;nt<4;++nt) bf[nt] = *frag64(Bs, n0w+nt*16+ln, c16);
      #pragma unroll
      for (int mt=0;mt<4;++mt)
        #pragma unroll
        for (int nt=0;nt<4;++nt)
          acc[mt][nt] = MFMA16(af[mt], bf[nt], acc[mt][nt]);
    }
  }
  #pragma unroll
  for (int mt=0;mt<4;++mt){
    #pragma unroll
    for (int nt=0;nt<4;++nt){
      const int col = n0 + n0w + nt*16 + ln;
      const float bn = bias_on_m ? 0.f : bias[col]*bscale;
      #pragma unroll
      for (int r=0;r<4;++r){
        const int row = m0 + m0w + mt*16 + quad*4 + r;
        const float bb = bias_on_m ? bias[row]*bscale : bn;
        const float val = acc[mt][nt][r] + bb;
        const size_t idx = cbase + (size_t)row*N + col;
        if (F32OUT) ((float*)Cv)[idx] = val;
        else        ((u16*)Cv)[idx]   = f2b(val);
      }
    }
  }
}

// ================= PROJ: Q,K,V projections in one uniform dispatch (768 blocks) ===========
// zone = bx>>7: 0..3 = (Q|K) x batch -> C[s][o]; 4..5 = V x batch -> C[o][s]
__global__ __launch_bounds__(256,3) void proj(
    const u16* __restrict__ qT, const u16* __restrict__ kT, const u16* __restrict__ vT,
    const u16* __restrict__ W16,
    const float* __restrict__ bq, const float* __restrict__ bk, const float* __restrict__ bv,
    u16* __restrict__ Qb, u16* __restrict__ Kb, u16* __restrict__ Vb)
{
  __shared__ __align__(16) u16 As[128*64];
  __shared__ __align__(16) u16 Bs[128*64];
  const int bx = blockIdx.x;
  const int zone = bx>>7, r = bx&127;
  const size_t sSE = (size_t)2048*1024;
  const int nW = 1024*1024;
  if (zone < 4){
    const int sel = zone>>1, b = zone&1;
    const int m0 = (r>>3)*128, n0 = (r&7)*128;
    gemm_core<false>((sel? kT : qT) + b*sSE, W16 + (size_t)sel*nW, sel? bk : bq,
                     sel? 1.0f : 0.18033688f, sel? Kb : Qb, b*sSE,
                     1024, 1024, 0, m0, n0, As, Bs);
  } else {
    const int b = zone&1;
    const int m0 = (r>>4)*128, n0 = (r&15)*128;
    gemm_core<false>(W16 + (size_t)2*nW, vT + b*sSE, bv,
                     1.0f, Vb, b*sSE,
                     2048, 1024, 1, m0, n0, As, Bs);
  }
}

// ================= OUT GEMM: 64x128 tiles for 512-block fill ==============================
// out[b][o][s] f32 = Wo[o][c] * attnT[b][s][c]^T + bo ; grid (S/128, E/64, B)
__global__ __launch_bounds__(256,4) void gemm_out64(
    const u16* __restrict__ Wo16, const u16* __restrict__ At, const float* __restrict__ bo,
    float* __restrict__ out)
{
  __shared__ __align__(16) u16 As[64*64];
  __shared__ __align__(16) u16 Bs[128*64];
  const int b = blockIdx.z;
  const int m0 = blockIdx.y*64, n0 = blockIdx.x*128;
  const size_t sSE = (size_t)2048*1024;
  const int K = 1024, N = 2048;
  const u16* Bt = At + b*sSE;
  const int tid = threadIdx.x, w = tid>>6, lane = tid&63;
  const int ln = lane&15, quad = lane>>4;
  const int m0w = (w>>1)*32, n0w = (w&1)*64;
  f32x4 acc[2][4];
  #pragma unroll
  for(int i=0;i<2;++i)
    #pragma unroll
    for(int j=0;j<4;++j) acc[i][j] = f32x4{0.f,0.f,0.f,0.f};

  for (int kc=0; kc<K; kc+=64){
    __syncthreads();
    stage64x64_sw (Wo16 + (size_t)m0*K + kc, As, K, w, lane);
    stage128x64_sw(Bt   + (size_t)n0*K + kc, Bs, K, w, lane);
    __syncthreads();
    #pragma unroll
    for (int kk=0; kk<64; kk+=32){
      const int c16 = (kk>>3) + quad;
      short8 af[2], bf[4];
      #pragma unroll
      for (int mt=0;mt<2;++mt) af[mt] = *frag64(As, m0w+mt*16+ln, c16);
      #pragma unroll
      for (int nt=0;nt<4;++nt) bf[nt] = *frag64(Bs, n0w+nt*16+ln, c16);
      #pragma unroll
      for (int mt=0;mt<2;++mt)
        #pragma unroll
        for (int nt=0;nt<4;++nt)
          acc[mt][nt] = MFMA16(af[mt], bf[nt], acc[mt][nt]);
    }
  }
  #pragma unroll
  for (int mt=0;mt<2;++mt){
    #pragma unroll
    for (int nt=0;nt<4;++nt){
      const int col = n0 + n0w + nt*16 + ln;
      #pragma unroll
      for (int r=0;r<4;++r){
        const int row = m0 + m0w + mt*16 + quad*4 + r;
        out[b*sSE + (size_t)row*N + col] = acc[mt][nt][r] + bo[row];
      }
    }
  }
}

// ================= fused flash attention, uniform-work blocks =============================
__global__ __launch_bounds__(256,2) void attn(
    const u16* __restrict__ Qb, const u16* __restrict__ Kb, const u16* __restrict__ Vb,
    const float* __restrict__ qk_mask, const float* __restrict__ k_mask,
    const char* __restrict__ classes, u16* __restrict__ Ot)
{
  __shared__ __align__(16) u16 Ks[128*64];
  __shared__ __align__(16) u16 Vs[64*128];
  const int x = blockIdx.x;
  const int b = x&1, h = (x>>1)&15;
  const int pp = x>>5, pair = pp>>1, half = pp&1;
  const int tid = threadIdx.x, w = tid>>6, lane = tid&63;
  const int ln = lane&15, quad = lane>>4;
  const int S = 2048;
  const float LOG2E = 1.44269504f, C2 = 16.0f;

  #pragma unroll
  for (int sub=0; sub<2; ++sub){
    const int qt = sub ? pair : (15-pair);
    const int qbase = qt*128 + half*64;
    const int qg = qbase + w*16 + ln;
    short8 qf[2];
    #pragma unroll
    for (int kkI=0;kkI<2;++kkI)
      qf[kkI] = *(const short8*)&Qb[((size_t)b*S + qg)*1024 + h*64 + kkI*32 + quad*8];

    const char* cl = classes + ((size_t)b*32 + qt*2 + half)*32;
    float rs = 0.f;
    f32x4 acc[4];
    #pragma unroll
    for (int ct=0;ct<4;++ct) acc[ct] = f32x4{0.f,0.f,0.f,0.f};

    for (int kt=0; kt<16; ++kt){
      const char c0 = cl[2*kt], c1 = cl[2*kt+1];
      if (c0==2 && c1==2) continue;
      const bool nomask = (c0|c1)==0;
      const int k0 = kt*128;
      __syncthreads();
      stage128x64_sw(Kb + ((size_t)b*S + k0)*1024 + h*64, Ks, 1024, w, lane);
      stage64x128_sw(Vb + ((size_t)b*1024 + h*64)*S + k0, Vs, S, w, lane);
      __syncthreads();

      unsigned pk[8][2];
      #pragma unroll
      for (int t=0;t<8;++t){
        f32x4 s = f32x4{0.f,0.f,0.f,0.f};
        #pragma unroll
        for (int kkI=0;kkI<2;++kkI)
          s = MFMA16(*frag64(Ks, t*16+ln, kkI*4 + quad), qf[kkI], s);
        float e[4];
        if (nomask){
          #pragma unroll
          for (int r=0;r<4;++r) e[r] = EXP2F(s[r] - C2);
        } else {
          #pragma unroll
          for (int r=0;r<4;++r){
            const int kg = k0 + t*16 + quad*4 + r;
            const float m = qk_mask[((size_t)b*S + kg)*S + qg] + k_mask[(size_t)b*S + kg];
            e[r] = EXP2F(fmaf(m, LOG2E, s[r]) - C2);
          }
        }
        rs += (e[0]+e[1]) + (e[2]+e[3]);
        pk[t][0] = pack_bf16(e[0], e[1]);
        pk[t][1] = pack_bf16(e[2], e[3]);
      }
      const int srcA = (quad&1)*32 + ln, srcB = srcA + 16;
      const bool hi = (quad>>1)&1;
      #pragma unroll
      for (int c=0;c<4;++c){
        unsigned a0 = __shfl((int)pk[2*c][0],   srcA, 64);
        unsigned a1 = __shfl((int)pk[2*c][1],   srcA, 64);
        unsigned a2 = __shfl((int)pk[2*c][0],   srcB, 64);
        unsigned a3 = __shfl((int)pk[2*c][1],   srcB, 64);
        unsigned b0 = __shfl((int)pk[2*c+1][0], srcA, 64);
        unsigned b1 = __shfl((int)pk[2*c+1][1], srcA, 64);
        unsigned b2 = __shfl((int)pk[2*c+1][0], srcB, 64);
        unsigned b3 = __shfl((int)pk[2*c+1][1], srcB, 64);
        short8 pf;
        ((unsigned*)&pf)[0] = hi ? b0 : a0;
        ((unsigned*)&pf)[1] = hi ? b1 : a1;
        ((unsigned*)&pf)[2] = hi ? b2 : a2;
        ((unsigned*)&pf)[3] = hi ? b3 : a3;
        #pragma unroll
        for (int ct=0;ct<4;++ct)
          acc[ct] = MFMA16(*frag128(Vs, ct*16+ln, c*4 + quad), pf, acc[ct]);
      }
    }
    rs += __shfl_xor(rs, 16, 64);
    rs += __shfl_xor(rs, 32, 64);
    const float rinv = 1.0f / rs;
    #pragma unroll
    for (int ct=0;ct<4;++ct){
      short4v o4;
      #pragma unroll
      for (int r=0;r<4;++r) o4[r] = (short)f2b(acc[ct][r] * rinv);
      *(short4v*)&Ot[((size_t)b*S + qg)*1024 + h*64 + ct*16 + quad*4] = o4;
    }
  }
}

extern "C" void kernel_launch(void* const* d_in, const int* in_sizes, int n_in,
                              void* d_out, int out_size, void* d_ws, size_t ws_size,
                              hipStream_t stream)
{
  const float* q   = (const float*)d_in[0];
  const float* k   = (const float*)d_in[1];
  const float* v   = (const float*)d_in[2];
  const float* qkm = (const float*)d_in[3];
  const float* km  = (const float*)d_in[4];
  const float* Wq  = (const float*)d_in[5];
  const float* bq  = (const float*)d_in[6];
  const float* Wk  = (const float*)d_in[7];
  const float* bk  = (const float*)d_in[8];
  const float* Wv  = (const float*)d_in[9];
  const float* bv  = (const float*)d_in[10];
  const float* Wo  = (const float*)d_in[11];
  const float* bo  = (const float*)d_in[12];
  float* out = (float*)d_out;

  const size_t nAct = (size_t)2*2048*1024;   // 4M elems per activation buffer
  const int   nW   = 1024*1024;

  u16* A0 = (u16*)d_ws;          // qT, later attn output Ot
  u16* A1 = A0 + nAct;           // kT
  u16* A2 = A1 + nAct;           // vT
  u16* A3 = A2 + nAct;           // Qb
  u16* A4 = A3 + nAct;           // Kb
  u16* A5 = A4 + nAct;           // Vb
  u16* W16 = A5 + nAct;          // Wq16|Wk16|Wv16|Wo16
  char* classes = (char*)(W16 + (size_t)4*nW);   // 2 KB
  u16* Wo16 = W16 + (size_t)3*nW;

  dim3 blk(256);
  prep      <<<dim3(7168), blk, 0, stream>>>(q, k, v, qkm, km, Wq, Wk, Wv, Wo,
                                             W16, classes, A0, A1, A2);
  proj      <<<dim3(768),  blk, 0, stream>>>(A0, A1, A2, W16, bq, bk, bv, A3, A4, A5);
  attn      <<<dim3(512),  blk, 0, stream>>>(A3, A4, A5, qkm, km, classes, A0);
  gemm_out64<<<dim3(16,16,2), blk, 0, stream>>>(Wo16, A0, bo, out);
}